// Round 1
// baseline (162.637 us; speedup 1.0000x reference)
//
#include <hip/hip_runtime.h>
#include <hip/hip_bf16.h>

typedef __bf16 bf16_t;
typedef __bf16 bf16x4 __attribute__((ext_vector_type(4)));
typedef __bf16 bf16x8 __attribute__((ext_vector_type(8)));
typedef float f32x4 __attribute__((ext_vector_type(4)));

#define M_TOT 8192
#define N_TOT 512
#define K_TOT 2048
#define E_TOT 512

#define BM 64
#define BN 128
#define BK 64
#define LDK 72  // BK + 8 pad (bf16 elems): row stride 144B -> <=2-way bank alias

// ---------------------------------------------------------------------------
// prep: z[m][q] = cos(theta[q]) * cos(x[m*512+q])   (algebraic collapse of the
//       RX-rotation |a2|^2-|b2|^2 = cos(theta)*cos(x))
//       W2t[n][k] = (bf16) W2[k][n]   (transpose so GEMM B-frags read
//       contiguous k via ds_read_b128)
// ---------------------------------------------------------------------------
__global__ void prep_kernel(const float* __restrict__ x,
                            const float* __restrict__ theta,
                            const float* __restrict__ W2,
                            bf16_t* __restrict__ W2t,
                            float* __restrict__ z)
{
    const int NZ = M_TOT * 8;          // 65536
    const int NW = N_TOT * K_TOT;      // 1048576
    int stride = gridDim.x * blockDim.x;
    for (int i = blockIdx.x * blockDim.x + threadIdx.x; i < NZ + NW; i += stride) {
        if (i < NZ) {
            int m = i >> 3, q = i & 7;
            z[i] = __builtin_cosf(theta[q]) * __builtin_cosf(x[m * E_TOT + q]);
        } else {
            int o = i - NZ;
            int n = o >> 11;           // / K_TOT
            int k = o & (K_TOT - 1);
            W2t[o] = (bf16_t)W2[k * N_TOT + n];
        }
    }
}

// ---------------------------------------------------------------------------
// fused GEMM: out[m][n] = sum_k relu(z[m]@W1[:,k]+b1[k]) * W2[k][n] + b2[n]
// 64x128 tile, BK=64, 256 threads = 4 waves (2x2), each wave 32x64 (acc[2][4])
// A-tile (h) computed on the fly: z rows live in registers for whole K-loop.
// ---------------------------------------------------------------------------
__global__ __launch_bounds__(256, 2)
void gemm_kernel(const float* __restrict__ z,    // [M_TOT][8]
                 const float* __restrict__ W1,   // [8][K_TOT]
                 const float* __restrict__ b1,   // [K_TOT]
                 const bf16_t* __restrict__ W2t, // [N_TOT][K_TOT]
                 const float* __restrict__ b2,   // [N_TOT]
                 float* __restrict__ out)        // [M_TOT][N_TOT]
{
    __shared__ bf16_t Alds[BM][LDK];
    __shared__ bf16_t Blds[BN][LDK];

    const int t = threadIdx.x;
    const int m_base = blockIdx.y * BM;
    const int n_base = blockIdx.x * BN;

    // ---- h-compute mapping: thread = (mg, fg); 4 rows x 4 f-cols each ----
    const int fg = t & 15;   // f-group: f = k0 + fg*4 .. +4
    const int mg = t >> 4;   // m-group: rows mg*4 .. +4

    // z rows for this thread, held in registers across the whole K loop
    float zr[4][8];
#pragma unroll
    for (int i = 0; i < 4; ++i) {
        const float4* zp = (const float4*)(z + (size_t)(m_base + mg * 4 + i) * 8);
        float4 z0 = zp[0];
        float4 z1 = zp[1];
        zr[i][0] = z0.x; zr[i][1] = z0.y; zr[i][2] = z0.z; zr[i][3] = z0.w;
        zr[i][4] = z1.x; zr[i][5] = z1.y; zr[i][6] = z1.z; zr[i][7] = z1.w;
    }

    // ---- MFMA mapping: wave (wm, wn) in 2x2; wave tile 32m x 64n ----
    const int w    = t >> 6;
    const int lane = t & 63;
    const int wm   = w >> 1;       // 0..1
    const int wn   = w & 1;        // 0..1
    const int l15  = lane & 15;
    const int lq   = lane >> 4;    // 0..3

    f32x4 acc[2][4];
#pragma unroll
    for (int mt = 0; mt < 2; ++mt)
#pragma unroll
        for (int nt = 0; nt < 4; ++nt)
            acc[mt][nt] = (f32x4){0.f, 0.f, 0.f, 0.f};

    for (int k0 = 0; k0 < K_TOT; k0 += BK) {
        // ---- stage B: Blds[n][k] <- W2t[n_base+n][k0+k], 128x64 bf16 ----
#pragma unroll
        for (int i = 0; i < 4; ++i) {
            int s   = t + i * 256;     // 0..1023
            int n   = s >> 3;          // 0..127
            int seg = s & 7;           // 8 bf16 (16B) per seg
            const uint4* gp = (const uint4*)(W2t + (size_t)(n_base + n) * K_TOT + k0 + seg * 8);
            *(uint4*)&Blds[n][seg * 8] = *gp;
        }

        // ---- stage A: h = relu(z @ W1 + b1), bf16 into Alds ----
        const int f0 = k0 + fg * 4;
        float4 b1v = *(const float4*)(b1 + f0);
        float4 w1q[8];
#pragma unroll
        for (int q = 0; q < 8; ++q)
            w1q[q] = *(const float4*)(W1 + q * K_TOT + f0);
#pragma unroll
        for (int i = 0; i < 4; ++i) {
            float h0 = b1v.x, h1 = b1v.y, h2 = b1v.z, h3 = b1v.w;
#pragma unroll
            for (int q = 0; q < 8; ++q) {
                float zv = zr[i][q];
                h0 += zv * w1q[q].x;
                h1 += zv * w1q[q].y;
                h2 += zv * w1q[q].z;
                h3 += zv * w1q[q].w;
            }
            h0 = fmaxf(h0, 0.f); h1 = fmaxf(h1, 0.f);
            h2 = fmaxf(h2, 0.f); h3 = fmaxf(h3, 0.f);
            bf16x4 hv;
            hv[0] = (bf16_t)h0; hv[1] = (bf16_t)h1;
            hv[2] = (bf16_t)h2; hv[3] = (bf16_t)h3;
            *(bf16x4*)&Alds[mg * 4 + i][fg * 4] = hv;
        }

        __syncthreads();

        // ---- MFMA inner loop over kk ----
#pragma unroll
        for (int kk = 0; kk < BK; kk += 32) {
            bf16x8 af[2], bfr[4];
#pragma unroll
            for (int mt = 0; mt < 2; ++mt)
                af[mt] = *(const bf16x8*)&Alds[wm * 32 + mt * 16 + l15][kk + lq * 8];
#pragma unroll
            for (int nt = 0; nt < 4; ++nt)
                bfr[nt] = *(const bf16x8*)&Blds[wn * 64 + nt * 16 + l15][kk + lq * 8];
#pragma unroll
            for (int mt = 0; mt < 2; ++mt)
#pragma unroll
                for (int nt = 0; nt < 4; ++nt)
                    acc[mt][nt] = __builtin_amdgcn_mfma_f32_16x16x32_bf16(
                        af[mt], bfr[nt], acc[mt][nt], 0, 0, 0);
        }

        __syncthreads();
    }

    // ---- epilogue: out = acc + b2, C/D layout col=lane&15 row=(lane>>4)*4+r ----
#pragma unroll
    for (int nt = 0; nt < 4; ++nt) {
        int col = n_base + wn * 64 + nt * 16 + l15;
        float bias = b2[col];
#pragma unroll
        for (int mt = 0; mt < 2; ++mt) {
#pragma unroll
            for (int r = 0; r < 4; ++r) {
                int row = m_base + wm * 32 + mt * 16 + lq * 4 + r;
                out[(size_t)row * N_TOT + col] = acc[mt][nt][r] + bias;
            }
        }
    }
}

extern "C" void kernel_launch(void* const* d_in, const int* in_sizes, int n_in,
                              void* d_out, int out_size, void* d_ws, size_t ws_size,
                              hipStream_t stream) {
    const float* x     = (const float*)d_in[0];
    const float* theta = (const float*)d_in[1];
    const float* W1    = (const float*)d_in[2];
    const float* b1    = (const float*)d_in[3];
    const float* W2    = (const float*)d_in[4];
    const float* b2    = (const float*)d_in[5];
    float* out = (float*)d_out;

    // ws layout: [0, 2MB) W2t bf16 ; [2MB, 2.25MB) z fp32
    bf16_t* W2t = (bf16_t*)d_ws;
    float*  z   = (float*)((char*)d_ws + (size_t)N_TOT * K_TOT * sizeof(bf16_t));

    prep_kernel<<<2048, 256, 0, stream>>>(x, theta, W2, W2t, z);

    dim3 grid(N_TOT / BN, M_TOT / BM);  // (4, 128)
    gemm_kernel<<<grid, 256, 0, stream>>>(z, W1, b1, W2t, b2, out);
}

// Round 2
// 124.803 us; speedup vs baseline: 1.3031x; 1.3031x over previous
//
#include <hip/hip_runtime.h>
#include <hip/hip_bf16.h>

typedef __bf16 bf16_t;
typedef __bf16 bf16x4 __attribute__((ext_vector_type(4)));
typedef __bf16 bf16x8 __attribute__((ext_vector_type(8)));
typedef float f32x4 __attribute__((ext_vector_type(4)));

#define M_TOT 8192
#define N_TOT 512
#define K_TOT 2048
#define E_TOT 512

// ---------------------------------------------------------------------------
// async global->LDS, 16B per lane. LDS dest = wave-uniform base + lane*16.
// ---------------------------------------------------------------------------
typedef const __attribute__((address_space(1))) void* gas_ptr;
typedef __attribute__((address_space(3))) void* las_ptr;

__device__ __forceinline__ void gload_lds16(const void* g, void* l) {
    __builtin_amdgcn_global_load_lds((gas_ptr)g, (las_ptr)l, 16, 0, 0);
}

// ---------------------------------------------------------------------------
// prep2: blocks [0,256): LDS-tiled coalesced transpose W2[k][n] -> W2t[n][k] bf16
//        blocks [256,512): z[m][q] = cos(theta[q]) * cos(x[m*512+q])
//        (algebraic collapse: |a2|^2-|b2|^2 = cos(theta)*cos(x))
// ---------------------------------------------------------------------------
__global__ __launch_bounds__(256)
void prep2_kernel(const float* __restrict__ x,
                  const float* __restrict__ theta,
                  const float* __restrict__ W2,
                  bf16_t* __restrict__ W2t,
                  float* __restrict__ z)
{
    if (blockIdx.x >= 256) {
        int i = (blockIdx.x - 256) * 256 + threadIdx.x;   // 0..65535
        int m = i >> 3, q = i & 7;
        z[i] = __builtin_cosf(theta[q]) * __builtin_cosf(x[(size_t)m * E_TOT + q]);
        return;
    }
    // transpose one 64k x 64n tile
    __shared__ bf16_t T[64][66];   // [n_local][k_local], +2 pad: bank step 1/row
    const int k0 = (blockIdx.x >> 3) * 64;
    const int n0 = (blockIdx.x & 7) * 64;
    const int kl = threadIdx.x >> 4;    // 0..15
    const int n4 = threadIdx.x & 15;    // 0..15
#pragma unroll
    for (int i = 0; i < 4; ++i) {
        int k = kl + i * 16;
        float4 v = *(const float4*)(W2 + (size_t)(k0 + k) * N_TOT + n0 + n4 * 4);
        T[n4 * 4 + 0][k] = (bf16_t)v.x;
        T[n4 * 4 + 1][k] = (bf16_t)v.y;
        T[n4 * 4 + 2][k] = (bf16_t)v.z;
        T[n4 * 4 + 3][k] = (bf16_t)v.w;
    }
    __syncthreads();
    const int nl = threadIdx.x >> 4;
    const int k4 = threadIdx.x & 15;
#pragma unroll
    for (int i = 0; i < 4; ++i) {
        int n = nl + i * 16;
        bf16x4 v;
        v[0] = T[n][k4 * 4 + 0];
        v[1] = T[n][k4 * 4 + 1];
        v[2] = T[n][k4 * 4 + 2];
        v[3] = T[n][k4 * 4 + 3];
        *(bf16x4*)(W2t + (size_t)(n0 + n) * K_TOT + k0 + k4 * 4) = v;
    }
}

// ---------------------------------------------------------------------------
// h_kernel: h[m][f] = relu(b1[f] + sum_q z[m][q]*W1[q][f]), bf16 out.
// Block = 256 threads, each owns 8 f-columns (W1 column chunk in 64 VGPRs),
// loops over 8 rows. Grid 1024. Write-bound (~32MB).
// ---------------------------------------------------------------------------
__global__ __launch_bounds__(256)
void h_kernel(const float* __restrict__ z,
              const float* __restrict__ W1,
              const float* __restrict__ b1,
              bf16_t* __restrict__ h)
{
    const int f0 = threadIdx.x * 8;
    float w[8][8];
#pragma unroll
    for (int q = 0; q < 8; ++q) {
        float4 a = *(const float4*)(W1 + (size_t)q * K_TOT + f0);
        float4 b = *(const float4*)(W1 + (size_t)q * K_TOT + f0 + 4);
        w[q][0] = a.x; w[q][1] = a.y; w[q][2] = a.z; w[q][3] = a.w;
        w[q][4] = b.x; w[q][5] = b.y; w[q][6] = b.z; w[q][7] = b.w;
    }
    float4 ba = *(const float4*)(b1 + f0);
    float4 bb = *(const float4*)(b1 + f0 + 4);
    float bias[8] = {ba.x, ba.y, ba.z, ba.w, bb.x, bb.y, bb.z, bb.w};

#pragma unroll
    for (int r = 0; r < 8; ++r) {
        int m = blockIdx.x * 8 + r;
        float4 z0 = *(const float4*)(z + (size_t)m * 8);
        float4 z1 = *(const float4*)(z + (size_t)m * 8 + 4);
        float zq[8] = {z0.x, z0.y, z0.z, z0.w, z1.x, z1.y, z1.z, z1.w};
        float acc[8];
#pragma unroll
        for (int j = 0; j < 8; ++j) acc[j] = bias[j];
#pragma unroll
        for (int q = 0; q < 8; ++q)
#pragma unroll
            for (int j = 0; j < 8; ++j)
                acc[j] += zq[q] * w[q][j];
        bf16x8 o;
#pragma unroll
        for (int j = 0; j < 8; ++j) o[j] = (bf16_t)fmaxf(acc[j], 0.f);
        *(bf16x8*)(h + (size_t)m * K_TOT + f0) = o;
    }
}

// ---------------------------------------------------------------------------
// gemm2: out = h @ W2t^T + b2.  64x128 tile, BK=64, 4 waves (2x2, 32x64 each).
// m97 recipe: global_load_lds width-16 staging + XOR-swizzled LDS (seg ^= row&7)
// so MFMA b128 reads are conflict-free without padding.
// ---------------------------------------------------------------------------
__global__ __launch_bounds__(256, 2)
void gemm2_kernel(const bf16_t* __restrict__ h,    // [8192][2048]
                  const bf16_t* __restrict__ W2t,  // [512][2048]
                  const float* __restrict__ b2,
                  float* __restrict__ out)         // [8192][512]
{
    __shared__ bf16_t Alds[64 * 64];    // [m][seg^(m&7)] 8 bf16/seg
    __shared__ bf16_t Blds[128 * 64];   // [n][seg^(n&7)]

    const int t = threadIdx.x;
    const int w = t >> 6, l = t & 63;
    const int m_base = blockIdx.y * 64;
    const int n_base = blockIdx.x * 128;
    const int wm = w >> 1, wn = w & 1;
    const int l15 = l & 15, lq = l >> 4;
    const int lrow = l >> 3, lseg = l & 7;

    f32x4 acc[2][4];
#pragma unroll
    for (int mt = 0; mt < 2; ++mt)
#pragma unroll
        for (int nt = 0; nt < 4; ++nt)
            acc[mt][nt] = (f32x4){0.f, 0.f, 0.f, 0.f};

    for (int k0 = 0; k0 < K_TOT; k0 += 64) {
        // stage A (64x64 bf16 = 8KB, 2 issues of 4KB)
#pragma unroll
        for (int j = 0; j < 2; ++j) {
            int m = j * 32 + w * 8 + lrow;
            int g = lseg ^ (m & 7);
            gload_lds16(h + (size_t)(m_base + m) * K_TOT + k0 + g * 8,
                        Alds + j * 2048 + w * 512);
        }
        // stage B (128x64 bf16 = 16KB, 4 issues)
#pragma unroll
        for (int j = 0; j < 4; ++j) {
            int n = j * 32 + w * 8 + lrow;
            int g = lseg ^ (n & 7);
            gload_lds16(W2t + (size_t)(n_base + n) * K_TOT + k0 + g * 8,
                        Blds + j * 2048 + w * 512);
        }
        __syncthreads();

#pragma unroll
        for (int kk = 0; kk < 2; ++kk) {
            bf16x8 af[2], bfr[4];
#pragma unroll
            for (int mt = 0; mt < 2; ++mt) {
                int r = wm * 32 + mt * 16 + l15;
                int s = (kk * 4 + lq) ^ (r & 7);
                af[mt] = *(const bf16x8*)(Alds + r * 64 + s * 8);
            }
#pragma unroll
            for (int nt = 0; nt < 4; ++nt) {
                int r = wn * 64 + nt * 16 + l15;
                int s = (kk * 4 + lq) ^ (r & 7);
                bfr[nt] = *(const bf16x8*)(Blds + r * 64 + s * 8);
            }
#pragma unroll
            for (int mt = 0; mt < 2; ++mt)
#pragma unroll
                for (int nt = 0; nt < 4; ++nt)
                    acc[mt][nt] = __builtin_amdgcn_mfma_f32_16x16x32_bf16(
                        af[mt], bfr[nt], acc[mt][nt], 0, 0, 0);
        }
        __syncthreads();
    }

    // epilogue: C/D layout col=lane&15, row=(lane>>4)*4+r
#pragma unroll
    for (int nt = 0; nt < 4; ++nt) {
        int col = n_base + wn * 64 + nt * 16 + l15;
        float bias = b2[col];
#pragma unroll
        for (int mt = 0; mt < 2; ++mt) {
#pragma unroll
            for (int r = 0; r < 4; ++r) {
                int row = m_base + wm * 32 + mt * 16 + lq * 4 + r;
                out[(size_t)row * N_TOT + col] = acc[mt][nt][r] + bias;
            }
        }
    }
}

// ---------------------------------------------------------------------------
// Fallback fused GEMM (round-1 path) for small ws_size: h computed on the fly.
// ---------------------------------------------------------------------------
#define BMf 64
#define BNf 128
#define LDKf 72

__global__ __launch_bounds__(256, 2)
void gemm_fused_kernel(const float* __restrict__ z,
                       const float* __restrict__ W1,
                       const float* __restrict__ b1,
                       const bf16_t* __restrict__ W2t,
                       const float* __restrict__ b2,
                       float* __restrict__ out)
{
    __shared__ bf16_t Alds[BMf][LDKf];
    __shared__ bf16_t Blds[BNf][LDKf];

    const int t = threadIdx.x;
    const int m_base = blockIdx.y * BMf;
    const int n_base = blockIdx.x * BNf;
    const int fg = t & 15;
    const int mg = t >> 4;

    float zr[4][8];
#pragma unroll
    for (int i = 0; i < 4; ++i) {
        const float4* zp = (const float4*)(z + (size_t)(m_base + mg * 4 + i) * 8);
        float4 z0 = zp[0];
        float4 z1 = zp[1];
        zr[i][0] = z0.x; zr[i][1] = z0.y; zr[i][2] = z0.z; zr[i][3] = z0.w;
        zr[i][4] = z1.x; zr[i][5] = z1.y; zr[i][6] = z1.z; zr[i][7] = z1.w;
    }

    const int w = t >> 6;
    const int lane = t & 63;
    const int wm = w >> 1, wn = w & 1;
    const int l15 = lane & 15, lq = lane >> 4;

    f32x4 acc[2][4];
#pragma unroll
    for (int mt = 0; mt < 2; ++mt)
#pragma unroll
        for (int nt = 0; nt < 4; ++nt)
            acc[mt][nt] = (f32x4){0.f, 0.f, 0.f, 0.f};

    for (int k0 = 0; k0 < K_TOT; k0 += 64) {
#pragma unroll
        for (int i = 0; i < 4; ++i) {
            int s = t + i * 256;
            int n = s >> 3;
            int seg = s & 7;
            const uint4* gp = (const uint4*)(W2t + (size_t)(n_base + n) * K_TOT + k0 + seg * 8);
            *(uint4*)&Blds[n][seg * 8] = *gp;
        }
        const int f0 = k0 + fg * 4;
        float4 b1v = *(const float4*)(b1 + f0);
        float4 w1q[8];
#pragma unroll
        for (int q = 0; q < 8; ++q)
            w1q[q] = *(const float4*)(W1 + q * K_TOT + f0);
#pragma unroll
        for (int i = 0; i < 4; ++i) {
            float h0 = b1v.x, h1 = b1v.y, h2 = b1v.z, h3 = b1v.w;
#pragma unroll
            for (int q = 0; q < 8; ++q) {
                float zv = zr[i][q];
                h0 += zv * w1q[q].x;
                h1 += zv * w1q[q].y;
                h2 += zv * w1q[q].z;
                h3 += zv * w1q[q].w;
            }
            h0 = fmaxf(h0, 0.f); h1 = fmaxf(h1, 0.f);
            h2 = fmaxf(h2, 0.f); h3 = fmaxf(h3, 0.f);
            bf16x4 hv;
            hv[0] = (bf16_t)h0; hv[1] = (bf16_t)h1;
            hv[2] = (bf16_t)h2; hv[3] = (bf16_t)h3;
            *(bf16x4*)&Alds[mg * 4 + i][fg * 4] = hv;
        }
        __syncthreads();
#pragma unroll
        for (int kk = 0; kk < 64; kk += 32) {
            bf16x8 af[2], bfr[4];
#pragma unroll
            for (int mt = 0; mt < 2; ++mt)
                af[mt] = *(const bf16x8*)&Alds[wm * 32 + mt * 16 + l15][kk + lq * 8];
#pragma unroll
            for (int nt = 0; nt < 4; ++nt)
                bfr[nt] = *(const bf16x8*)&Blds[wn * 64 + nt * 16 + l15][kk + lq * 8];
#pragma unroll
            for (int mt = 0; mt < 2; ++mt)
#pragma unroll
                for (int nt = 0; nt < 4; ++nt)
                    acc[mt][nt] = __builtin_amdgcn_mfma_f32_16x16x32_bf16(
                        af[mt], bfr[nt], acc[mt][nt], 0, 0, 0);
        }
        __syncthreads();
    }
#pragma unroll
    for (int nt = 0; nt < 4; ++nt) {
        int col = n_base + wn * 64 + nt * 16 + l15;
        float bias = b2[col];
#pragma unroll
        for (int mt = 0; mt < 2; ++mt) {
#pragma unroll
            for (int r = 0; r < 4; ++r) {
                int row = m_base + wm * 32 + mt * 16 + lq * 4 + r;
                out[(size_t)row * N_TOT + col] = acc[mt][nt][r] + bias;
            }
        }
    }
}

extern "C" void kernel_launch(void* const* d_in, const int* in_sizes, int n_in,
                              void* d_out, int out_size, void* d_ws, size_t ws_size,
                              hipStream_t stream) {
    const float* x     = (const float*)d_in[0];
    const float* theta = (const float*)d_in[1];
    const float* W1    = (const float*)d_in[2];
    const float* b1    = (const float*)d_in[3];
    const float* W2    = (const float*)d_in[4];
    const float* b2    = (const float*)d_in[5];
    float* out = (float*)d_out;

    // ws layout: [0,2MB) W2t bf16 ; [2MB,2.25MB) z f32 ; [2.25MB,34.25MB) h bf16
    const size_t W2T_BYTES = (size_t)N_TOT * K_TOT * sizeof(bf16_t);   // 2 MB
    const size_t Z_BYTES   = (size_t)M_TOT * 8 * sizeof(float);        // 256 KB
    const size_t H_BYTES   = (size_t)M_TOT * K_TOT * sizeof(bf16_t);   // 32 MB

    bf16_t* W2t = (bf16_t*)d_ws;
    float*  z   = (float*)((char*)d_ws + W2T_BYTES);
    bf16_t* h   = (bf16_t*)((char*)d_ws + W2T_BYTES + Z_BYTES);

    prep2_kernel<<<512, 256, 0, stream>>>(x, theta, W2, W2t, z);

    if (ws_size >= W2T_BYTES + Z_BYTES + H_BYTES) {
        h_kernel<<<M_TOT / 8, 256, 0, stream>>>(z, W1, b1, h);
        dim3 grid(N_TOT / 128, M_TOT / 64);   // (4, 128)
        gemm2_kernel<<<grid, 256, 0, stream>>>(h, W2t, b2, out);
    } else {
        dim3 grid(N_TOT / BNf, M_TOT / BMf);  // (4, 128)
        gemm_fused_kernel<<<grid, 256, 0, stream>>>(z, W1, b1, W2t, b2, out);
    }
}

// Round 3
// 114.462 us; speedup vs baseline: 1.4209x; 1.0903x over previous
//
#include <hip/hip_runtime.h>
#include <hip/hip_bf16.h>

typedef __bf16 bf16_t;
typedef __bf16 bf16x4 __attribute__((ext_vector_type(4)));
typedef __bf16 bf16x8 __attribute__((ext_vector_type(8)));
typedef float f32x4 __attribute__((ext_vector_type(4)));

#define M_TOT 8192
#define N_TOT 512
#define K_TOT 2048
#define E_TOT 512

// ---------------------------------------------------------------------------
// async global->LDS, 16B per lane. LDS dest = wave-uniform base + lane*16.
// ---------------------------------------------------------------------------
typedef const __attribute__((address_space(1))) void* gas_ptr;
typedef __attribute__((address_space(3))) void* las_ptr;

__device__ __forceinline__ void gload_lds16(const void* g, void* l) {
    __builtin_amdgcn_global_load_lds((gas_ptr)g, (las_ptr)l, 16, 0, 0);
}

__device__ __forceinline__ bf16x8 zero8() {
    bf16x8 v;
#pragma unroll
    for (int i = 0; i < 8; ++i) v[i] = (bf16_t)0.0f;
    return v;
}

// ---------------------------------------------------------------------------
// prep3:
//  blocks [0,256):   LDS-tiled transpose W2[k][n] -> W2t[n][k] bf16
//  blocks [256,288): zb[m][0..8) = cos(theta[q])*cos(x[m,q])  (RX collapse:
//                    |a2|^2-|b2|^2 = cos(theta)*cos(x)); zb[m][8] = 1 (bias
//                    lane), zb[m][9..16) = 0.  Row = 16 bf16 = 32B.
//  blocks [288,296): W1t[f][0..8) = W1[q][f]; W1t[f][8] = b1[f]; rest 0.
// ---------------------------------------------------------------------------
__global__ __launch_bounds__(256)
void prep3_kernel(const float* __restrict__ x,
                  const float* __restrict__ theta,
                  const float* __restrict__ W1,
                  const float* __restrict__ b1,
                  const float* __restrict__ W2,
                  bf16_t* __restrict__ W2t,
                  bf16_t* __restrict__ zb,
                  bf16_t* __restrict__ W1t)
{
    const int b = blockIdx.x;
    if (b < 256) {
        // transpose one 64k x 64n tile of W2
        __shared__ bf16_t T[64][66];
        const int k0 = (b >> 3) * 64;
        const int n0 = (b & 7) * 64;
        const int kl = threadIdx.x >> 4;
        const int n4 = threadIdx.x & 15;
#pragma unroll
        for (int i = 0; i < 4; ++i) {
            int k = kl + i * 16;
            float4 v = *(const float4*)(W2 + (size_t)(k0 + k) * N_TOT + n0 + n4 * 4);
            T[n4 * 4 + 0][k] = (bf16_t)v.x;
            T[n4 * 4 + 1][k] = (bf16_t)v.y;
            T[n4 * 4 + 2][k] = (bf16_t)v.z;
            T[n4 * 4 + 3][k] = (bf16_t)v.w;
        }
        __syncthreads();
        const int nl = threadIdx.x >> 4;
        const int k4 = threadIdx.x & 15;
#pragma unroll
        for (int i = 0; i < 4; ++i) {
            int n = nl + i * 16;
            bf16x4 v;
            v[0] = T[n][k4 * 4 + 0];
            v[1] = T[n][k4 * 4 + 1];
            v[2] = T[n][k4 * 4 + 2];
            v[3] = T[n][k4 * 4 + 3];
            *(bf16x4*)(W2t + (size_t)(n0 + n) * K_TOT + k0 + k4 * 4) = v;
        }
    } else if (b < 288) {
        const int m = (b - 256) * 256 + threadIdx.x;     // 0..8191
        float4 x0 = *(const float4*)(x + (size_t)m * E_TOT);
        float4 x1 = *(const float4*)(x + (size_t)m * E_TOT + 4);
        float xs[8] = {x0.x, x0.y, x0.z, x0.w, x1.x, x1.y, x1.z, x1.w};
        bf16x8 lo;
#pragma unroll
        for (int q = 0; q < 8; ++q)
            lo[q] = (bf16_t)(__builtin_cosf(theta[q]) * __builtin_cosf(xs[q]));
        bf16x8 hi = zero8();
        hi[0] = (bf16_t)1.0f;                            // bias lane (k=8)
        *(bf16x8*)(zb + (size_t)m * 16)     = lo;
        *(bf16x8*)(zb + (size_t)m * 16 + 8) = hi;
    } else {
        const int f = (b - 288) * 256 + threadIdx.x;     // 0..2047
        bf16x8 lo;
#pragma unroll
        for (int q = 0; q < 8; ++q)
            lo[q] = (bf16_t)W1[(size_t)q * K_TOT + f];
        bf16x8 hi = zero8();
        hi[0] = (bf16_t)b1[f];                           // bias at k=8
        *(bf16x8*)(W1t + (size_t)f * 16)     = lo;
        *(bf16x8*)(W1t + (size_t)f * 16 + 8) = hi;
    }
}

// ---------------------------------------------------------------------------
// Fully fused: out[m][n] = relu(z[m]@W1 + b1) @ W2 + b2, one kernel.
// 64x128 block tile, BK=64, 4 waves (2x2, each 32x64 of output).
//
// Per K-tile:
//   1. load W1t A-frags (L1-hot, issued BEFORE gload so waitcnt doesn't
//      drain the async queue)
//   2. async-stage B tile (W2t) via global_load_lds, xor-swizzled
//   3. h-tile via MFMA: h^T(f x m) = W1t(f x q) @ z^T(q x m), q padded to 32
//      with bias folded at q=8.  D layout: col=m, row=4 consecutive f ->
//      relu+cvt -> ONE ds_write_b64 per MFMA into swizzled Alds.
//   4. barrier; 16 main MFMAs from Alds/Blds; barrier.
// ---------------------------------------------------------------------------
__global__ __launch_bounds__(256, 2)
void ffq_gemm_kernel(const bf16_t* __restrict__ zb,    // [8192][16]
                     const bf16_t* __restrict__ W1t,   // [2048][16]
                     const bf16_t* __restrict__ W2t,   // [512][2048]
                     const float* __restrict__ b2,
                     float* __restrict__ out)          // [8192][512]
{
    __shared__ bf16_t Alds[64 * 64];    // h tile  [m][slot = fseg ^ (m&7)]
    __shared__ bf16_t Blds[128 * 64];   // W2 tile [n][slot = kseg ^ (n&7)]

    const int t = threadIdx.x;
    const int w = t >> 6, l = t & 63;
    const int m_base = blockIdx.y * 64;
    const int n_base = blockIdx.x * 128;
    const int wm = w >> 1, wn = w & 1;
    const int l15 = l & 15, lq = l >> 4;
    const int lrow = l >> 3, lseg = l & 7;

    // z^T B-frag: lane l15 holds z[m_base + w*16 + l15][k = lq*8 + j].
    // Real data only for k<16 (q<8 plus bias lane at k=8); quads 2,3 = 0.
    bf16x8 zfrag = zero8();
    if (lq < 2)
        zfrag = *(const bf16x8*)(zb + (size_t)(m_base + w * 16 + l15) * 16 + lq * 8);

    f32x4 acc[2][4];
#pragma unroll
    for (int mt = 0; mt < 2; ++mt)
#pragma unroll
        for (int nt = 0; nt < 4; ++nt)
            acc[mt][nt] = (f32x4){0.f, 0.f, 0.f, 0.f};

    for (int k0 = 0; k0 < K_TOT; k0 += 64) {
        // ---- 1. W1t A-frags: A[f = ft*16 + l15][k = lq*8 + j] ----
        bf16x8 wf[4];
#pragma unroll
        for (int ft = 0; ft < 4; ++ft) wf[ft] = zero8();
        if (lq < 2) {
#pragma unroll
            for (int ft = 0; ft < 4; ++ft)
                wf[ft] = *(const bf16x8*)(W1t + (size_t)(k0 + ft * 16 + l15) * 16 + lq * 8);
        }

        // ---- 2. stage B (128x64 bf16 = 16KB, 4 wave-issues each) ----
#pragma unroll
        for (int j = 0; j < 4; ++j) {
            int n = j * 32 + w * 8 + lrow;
            int g = lseg ^ (n & 7);
            gload_lds16(W2t + (size_t)(n_base + n) * K_TOT + k0 + g * 8,
                        (bf16_t*)Blds + j * 2048 + w * 512);
        }

        // ---- 3. h tile via MFMA; wave w owns m rows w*16..w*16+16 ----
        const int m_loc = w * 16 + l15;
#pragma unroll
        for (int ft = 0; ft < 4; ++ft) {
            f32x4 hacc = (f32x4){0.f, 0.f, 0.f, 0.f};
            hacc = __builtin_amdgcn_mfma_f32_16x16x32_bf16(wf[ft], zfrag, hacc, 0, 0, 0);
            // lane output: h[m_loc][f = ft*16 + lq*4 + r], r=0..3
            bf16x4 hv;
#pragma unroll
            for (int r = 0; r < 4; ++r) hv[r] = (bf16_t)fmaxf(hacc[r], 0.f);
            int fseg = ft * 2 + (lq >> 1);          // (f>>3)
            int slot = fseg ^ (m_loc & 7);
            *(bf16x4*)(Alds + m_loc * 64 + slot * 8 + (lq & 1) * 4) = hv;
        }

        __syncthreads();   // drains gload vmcnt + h ds_writes

        // ---- 4. main MFMAs ----
#pragma unroll
        for (int kk = 0; kk < 2; ++kk) {
            bf16x8 af[2], bfr[4];
#pragma unroll
            for (int mt = 0; mt < 2; ++mt) {
                int r = wm * 32 + mt * 16 + l15;
                int s = (kk * 4 + lq) ^ (r & 7);
                af[mt] = *(const bf16x8*)(Alds + r * 64 + s * 8);
            }
#pragma unroll
            for (int nt = 0; nt < 4; ++nt) {
                int r = wn * 64 + nt * 16 + l15;
                int s = (kk * 4 + lq) ^ (r & 7);
                bfr[nt] = *(const bf16x8*)(Blds + r * 64 + s * 8);
            }
#pragma unroll
            for (int mt = 0; mt < 2; ++mt)
#pragma unroll
                for (int nt = 0; nt < 4; ++nt)
                    acc[mt][nt] = __builtin_amdgcn_mfma_f32_16x16x32_bf16(
                        af[mt], bfr[nt], acc[mt][nt], 0, 0, 0);
        }
        __syncthreads();
    }

    // ---- epilogue: C/D layout col=lane&15, row=(lane>>4)*4+r ----
#pragma unroll
    for (int nt = 0; nt < 4; ++nt) {
        int col = n_base + wn * 64 + nt * 16 + l15;
        float bias = b2[col];
#pragma unroll
        for (int mt = 0; mt < 2; ++mt) {
#pragma unroll
            for (int r = 0; r < 4; ++r) {
                int row = m_base + wm * 32 + mt * 16 + lq * 4 + r;
                out[(size_t)row * N_TOT + col] = acc[mt][nt][r] + bias;
            }
        }
    }
}

extern "C" void kernel_launch(void* const* d_in, const int* in_sizes, int n_in,
                              void* d_out, int out_size, void* d_ws, size_t ws_size,
                              hipStream_t stream) {
    const float* x     = (const float*)d_in[0];
    const float* theta = (const float*)d_in[1];
    const float* W1    = (const float*)d_in[2];
    const float* b1    = (const float*)d_in[3];
    const float* W2    = (const float*)d_in[4];
    const float* b2    = (const float*)d_in[5];
    float* out = (float*)d_out;

    // ws: [0,2MB) W2t ; [2MB,2.25MB) zb[8192][16] ; then W1t[2048][16]
    const size_t W2T_BYTES = (size_t)N_TOT * K_TOT * sizeof(bf16_t);  // 2 MB
    const size_t ZB_BYTES  = (size_t)M_TOT * 16 * sizeof(bf16_t);     // 256 KB

    bf16_t* W2t = (bf16_t*)d_ws;
    bf16_t* zb  = (bf16_t*)((char*)d_ws + W2T_BYTES);
    bf16_t* W1t = (bf16_t*)((char*)d_ws + W2T_BYTES + ZB_BYTES);

    prep3_kernel<<<296, 256, 0, stream>>>(x, theta, W1, b1, W2, W2t, zb, W1t);

    dim3 grid(N_TOT / 128, M_TOT / 64);   // (4, 128) = 512 blocks, 2/CU
    ffq_gemm_kernel<<<grid, 256, 0, stream>>>(zb, W1t, W2t, b2, out);
}